// Round 1
// baseline (255.221 us; speedup 1.0000x reference)
//
#include <hip/hip_runtime.h>
#include <hip/hip_bf16.h>
#include <cstdint>

// MultiHeadAttention fused pipeline for MI355X (gfx950).
// Phases: cvt(fp32->bf16) -> QKV GEMM (bias + scatter to Q/K/Vt bf16)
//         -> flash attention (causal, online softmax) -> out-proj GEMM (+bias, fp32 out).

#define DEV __device__ __forceinline__

using bf16x8 = __attribute__((ext_vector_type(8))) short;
using f32x4  = __attribute__((ext_vector_type(4))) float;

DEV unsigned short f2bf(float f) {
  unsigned u = __builtin_bit_cast(unsigned, f);
  u = (u + 0x7fffu + ((u >> 16) & 1u)) >> 16;  // RNE
  return (unsigned short)u;
}

typedef __attribute__((address_space(1))) unsigned int as1_uint;
typedef __attribute__((address_space(3))) unsigned int as3_uint;

// async global->LDS, 16B per lane. LDS dest must be uniform base + lane*16.
DEV void gload_lds16(const void* g, void* l) {
  __builtin_amdgcn_global_load_lds(
      (as1_uint*)(uintptr_t)g,
      (as3_uint*)(unsigned int)(uintptr_t)l,
      16, 0, 0);
}

__global__ __launch_bounds__(256) void cvt_f32_bf16_k(const float* __restrict__ in,
                                                      unsigned short* __restrict__ out,
                                                      int n4) {
  int i = blockIdx.x * 256 + threadIdx.x;
  if (i >= n4) return;
  float4 v = reinterpret_cast<const float4*>(in)[i];
  ushort4 o;
  o.x = f2bf(v.x); o.y = f2bf(v.y); o.z = f2bf(v.z); o.w = f2bf(v.w);
  reinterpret_cast<ushort4*>(out)[i] = o;
}

// C[M,N] = A[M,K](bf16) * W[N,K](bf16)^T + bias.
// MODE 0: Cout fp32 [M,N].  MODE 1: scatter to Q/K (b,h,s,d) and Vt (b,h,d,s) bf16.
// 128x128 tile, BK=64, 4 waves (2x2), 16x16x32 bf16 MFMA, global_load_lds staging.
template <int MODE, int N, int K>
__global__ __launch_bounds__(256) void gemm_bt(const unsigned short* __restrict__ A,
                                               const unsigned short* __restrict__ W,
                                               const float* __restrict__ bias,
                                               float* __restrict__ Cout,
                                               unsigned short* __restrict__ Qp,
                                               unsigned short* __restrict__ Kp,
                                               unsigned short* __restrict__ Vt) {
  __shared__ unsigned short As[128 * 64];
  __shared__ unsigned short Bs[128 * 64];
  const int tid = threadIdx.x;
  const int m0 = blockIdx.x * 128;
  const int n0 = blockIdx.y * 128;
  const int w = tid >> 6, lane = tid & 63, g = lane >> 4, lr = lane & 15;
  const int wr = w >> 1, wc = w & 1;

  f32x4 acc[4][4];
#pragma unroll
  for (int i = 0; i < 4; ++i)
#pragma unroll
    for (int j = 0; j < 4; ++j)
#pragma unroll
      for (int r = 0; r < 4; ++r) acc[i][j][r] = 0.f;

  for (int kt = 0; kt < K; kt += 64) {
    // stage A,B tiles: 1024 chunks of 16B each per tile, 4 per thread
#pragma unroll
    for (int it = 0; it < 4; ++it) {
      const int c = it * 256 + tid;
      const int row = c >> 3;
      const int colb = (c & 7) * 16;
      gload_lds16((const char*)(A + (size_t)(m0 + row) * K + kt) + colb, (char*)As + c * 16);
      gload_lds16((const char*)(W + (size_t)(n0 + row) * K + kt) + colb, (char*)Bs + c * 16);
    }
    __syncthreads();
#pragma unroll
    for (int ks = 0; ks < 2; ++ks) {
      bf16x8 af[4], bf[4];
#pragma unroll
      for (int mi = 0; mi < 4; ++mi)
        af[mi] = *(const bf16x8*)(As + (wr * 64 + mi * 16 + lr) * 64 + ks * 32 + g * 8);
#pragma unroll
      for (int ni = 0; ni < 4; ++ni)
        bf[ni] = *(const bf16x8*)(Bs + (wc * 64 + ni * 16 + lr) * 64 + ks * 32 + g * 8);
#pragma unroll
      for (int mi = 0; mi < 4; ++mi)
#pragma unroll
        for (int ni = 0; ni < 4; ++ni)
          acc[mi][ni] = __builtin_amdgcn_mfma_f32_16x16x32_bf16(af[mi], bf[ni], acc[mi][ni], 0, 0, 0);
    }
    __syncthreads();
  }

  if (MODE == 0) {
#pragma unroll
    for (int ni = 0; ni < 4; ++ni) {
      const int col = n0 + wc * 64 + ni * 16 + lr;
      const float bv = bias[col];
#pragma unroll
      for (int mi = 0; mi < 4; ++mi)
#pragma unroll
        for (int r = 0; r < 4; ++r) {
          const int row = m0 + wr * 64 + mi * 16 + g * 4 + r;
          Cout[(size_t)row * N + col] = acc[mi][ni][r] + bv;
        }
    }
  } else {
#pragma unroll
    for (int ni = 0; ni < 4; ++ni) {
      const int col = n0 + wc * 64 + ni * 16 + lr;
      const float bv = bias[col];
      const int which = col >> 10;
      const int h = (col >> 6) & 15;
      const int d = col & 63;
#pragma unroll
      for (int mi = 0; mi < 4; ++mi)
#pragma unroll
        for (int r = 0; r < 4; ++r) {
          const int row = m0 + wr * 64 + mi * 16 + g * 4 + r;
          const int b = row >> 11, s = row & 2047;
          const int bh = b * 16 + h;
          const unsigned short v = f2bf(acc[mi][ni][r] + bv);
          if (which == 0)      Qp[((size_t)bh * 2048 + s) * 64 + d] = v;
          else if (which == 1) Kp[((size_t)bh * 2048 + s) * 64 + d] = v;
          else                 Vt[((size_t)bh * 64 + d) * 2048 + s] = v;
        }
    }
  }
}

// Flash attention, causal. grid (B*H=32, S/64=32), 256 threads = 4 independent waves,
// each wave owns 16 q-rows. KV block = 64. Online softmax per q-row (replicated
// across the 16-lane group via shfl_xor). P staged via per-wave LDS (XOR-swizzled).
__global__ __launch_bounds__(256) void attn_fwd(const unsigned short* __restrict__ Q,
                                                const unsigned short* __restrict__ Kg,
                                                const unsigned short* __restrict__ Vt,
                                                unsigned short* __restrict__ AO) {
  const int bh = blockIdx.x;   // b*16 + h
  const int qb = blockIdx.y;
  const int tid = threadIdx.x;
  const int w = tid >> 6, lane = tid & 63, g = lane >> 4, lr = lane & 15;
  const int q0 = qb * 64;
  const int qrow0 = q0 + w * 16;
  const unsigned short* Qp = Q  + (size_t)bh * 2048 * 64;
  const unsigned short* Kp = Kg + (size_t)bh * 2048 * 64;
  const unsigned short* Vp = Vt + (size_t)bh * 64 * 2048;

  __shared__ unsigned short Pl[4][16 * 64];  // per-wave P tile (bf16)

  bf16x8 aq[2];
#pragma unroll
  for (int ks = 0; ks < 2; ++ks)
    aq[ks] = *(const bf16x8*)(Qp + (size_t)(qrow0 + lr) * 64 + ks * 32 + g * 8);

  f32x4 o[4];
  float m_r[4], l_r[4];
#pragma unroll
  for (int db = 0; db < 4; ++db)
#pragma unroll
    for (int r = 0; r < 4; ++r) o[db][r] = 0.f;
#pragma unroll
  for (int r = 0; r < 4; ++r) { m_r[r] = -INFINITY; l_r[r] = 0.f; }

  const int kv_end = q0 + 64;  // exclusive; uniform across block (barrier-safe)
  for (int kvb = 0; kvb < kv_end; kvb += 64) {
    f32x4 sc[4];
#pragma unroll
    for (int f = 0; f < 4; ++f)
#pragma unroll
      for (int r = 0; r < 4; ++r) sc[f][r] = 0.f;
#pragma unroll
    for (int ks = 0; ks < 2; ++ks)
#pragma unroll
      for (int f = 0; f < 4; ++f) {
        bf16x8 bk = *(const bf16x8*)(Kp + (size_t)(kvb + f * 16 + lr) * 64 + ks * 32 + g * 8);
        sc[f] = __builtin_amdgcn_mfma_f32_16x16x32_bf16(aq[ks], bk, sc[f], 0, 0, 0);
      }

#pragma unroll
    for (int r = 0; r < 4; ++r) {
      const int qrow = qrow0 + g * 4 + r;
      float mx = -INFINITY;
#pragma unroll
      for (int f = 0; f < 4; ++f) {
        float s = sc[f][r] * 0.125f;                 // 1/sqrt(64)
        if (kvb + f * 16 + lr > qrow) s = -INFINITY; // causal mask
        sc[f][r] = s;
        mx = fmaxf(mx, s);
      }
      mx = fmaxf(mx, __shfl_xor(mx, 1));
      mx = fmaxf(mx, __shfl_xor(mx, 2));
      mx = fmaxf(mx, __shfl_xor(mx, 4));
      mx = fmaxf(mx, __shfl_xor(mx, 8));
      const float mn = fmaxf(m_r[r], mx);
      const float sc_old = __expf(m_r[r] - mn);
      float ps = 0.f;
#pragma unroll
      for (int f = 0; f < 4; ++f) {
        float p = __expf(sc[f][r] - mn);
        sc[f][r] = p;
        ps += p;
      }
      ps += __shfl_xor(ps, 1); ps += __shfl_xor(ps, 2);
      ps += __shfl_xor(ps, 4); ps += __shfl_xor(ps, 8);
      l_r[r] = l_r[r] * sc_old + ps;
      m_r[r] = mn;
#pragma unroll
      for (int db = 0; db < 4; ++db) o[db][r] *= sc_old;
    }

    __syncthreads();  // protect Pl from previous iteration's readers
#pragma unroll
    for (int r = 0; r < 4; ++r) {
      const int prow = g * 4 + r;
#pragma unroll
      for (int f = 0; f < 4; ++f) {
        const int byte = (prow * 128 + (f * 16 + lr) * 2) ^ ((prow & 7) << 4);
        *(unsigned short*)((char*)Pl[w] + byte) = f2bf(sc[f][r]);
      }
    }
    __syncthreads();
#pragma unroll
    for (int ks = 0; ks < 2; ++ks) {
      const int byte = (lr * 128 + ks * 64 + g * 16) ^ ((lr & 7) << 4);
      bf16x8 pa = *(const bf16x8*)((const char*)Pl[w] + byte);
#pragma unroll
      for (int db = 0; db < 4; ++db) {
        bf16x8 bv = *(const bf16x8*)(Vp + (size_t)(db * 16 + lr) * 2048 + kvb + ks * 32 + g * 8);
        o[db] = __builtin_amdgcn_mfma_f32_16x16x32_bf16(pa, bv, o[db], 0, 0, 0);
      }
    }
  }

  const int b = bh >> 4, h = bh & 15;
#pragma unroll
  for (int r = 0; r < 4; ++r) {
    const float inv = 1.0f / l_r[r];
    const int row = qrow0 + g * 4 + r;
#pragma unroll
    for (int db = 0; db < 4; ++db)
      AO[(size_t)(b * 2048 + row) * 1024 + h * 64 + db * 16 + lr] = f2bf(o[db][r] * inv);
  }
}

extern "C" void kernel_launch(void* const* d_in, const int* in_sizes, int n_in,
                              void* d_out, int out_size, void* d_ws, size_t ws_size,
                              hipStream_t stream) {
  const float* x     = (const float*)d_in[0];
  const float* W_qkv = (const float*)d_in[1];
  const float* b_qkv = (const float*)d_in[2];
  const float* W_out = (const float*)d_in[3];
  const float* b_out = (const float*)d_in[4];
  float* out = (float*)d_out;

  // workspace layout (48 MB total, fully rewritten every call)
  char* ws = (char*)d_ws;
  unsigned short* xb  = (unsigned short*)(ws);                    // 8 MB x bf16 [4096,1024]
  unsigned short* wqb = (unsigned short*)(ws + ((size_t)8 << 20)); // 6 MB W_qkv bf16
  unsigned short* wob = (unsigned short*)(ws + ((size_t)14 << 20)); // 2 MB W_out bf16
  unsigned short* Qb  = (unsigned short*)(ws + ((size_t)16 << 20)); // 8 MB Q [b,h,s,d]
  unsigned short* Kb  = (unsigned short*)(ws + ((size_t)24 << 20)); // 8 MB K [b,h,s,d]
  unsigned short* Vtb = (unsigned short*)(ws + ((size_t)32 << 20)); // 8 MB V^T [b,h,d,s]
  unsigned short* AOb = (unsigned short*)(ws + ((size_t)40 << 20)); // 8 MB attn out [4096,1024]

  cvt_f32_bf16_k<<<4096, 256, 0, stream>>>(x, xb, 4096 * 1024 / 4);
  cvt_f32_bf16_k<<<3072, 256, 0, stream>>>(W_qkv, wqb, 3072 * 1024 / 4);
  cvt_f32_bf16_k<<<1024, 256, 0, stream>>>(W_out, wob, 1024 * 1024 / 4);

  gemm_bt<1, 3072, 1024><<<dim3(32, 24), 256, 0, stream>>>(xb, wqb, b_qkv, nullptr, Qb, Kb, Vtb);
  attn_fwd<<<dim3(32, 32), 256, 0, stream>>>(Qb, Kb, Vtb, AOb);
  gemm_bt<0, 1024, 1024><<<dim3(32, 8), 256, 0, stream>>>(AOb, wob, b_out, out, nullptr, nullptr, nullptr);
}

// Round 2
// 226.626 us; speedup vs baseline: 1.1262x; 1.1262x over previous
//
#include <hip/hip_runtime.h>
#include <hip/hip_bf16.h>
#include <cstdint>

// MultiHeadAttention fused pipeline for MI355X (gfx950).
// Phases: cvt(fp32->bf16) -> QKV GEMM (bias + scatter to Q/K/Vt bf16)
//         -> flash attention (causal, online softmax) -> out-proj GEMM (+bias, fp32 out).

#define DEV __device__ __forceinline__

using bf16x8 = __attribute__((ext_vector_type(8))) short;
using f32x4  = __attribute__((ext_vector_type(4))) float;

DEV unsigned short f2bf(float f) {
  unsigned u = __builtin_bit_cast(unsigned, f);
  u = (u + 0x7fffu + ((u >> 16) & 1u)) >> 16;  // RNE
  return (unsigned short)u;
}

typedef __attribute__((address_space(1))) unsigned int as1_uint;
typedef __attribute__((address_space(3))) unsigned int as3_uint;

// async global->LDS, 16B per lane. LDS dest must be uniform base + lane*16.
DEV void gload_lds16(const void* g, void* l) {
  __builtin_amdgcn_global_load_lds(
      (as1_uint*)(uintptr_t)g,
      (as3_uint*)(unsigned int)(uintptr_t)l,
      16, 0, 0);
}

__global__ __launch_bounds__(256) void cvt_f32_bf16_k(const float* __restrict__ in,
                                                      unsigned short* __restrict__ out,
                                                      int n4) {
  int i = blockIdx.x * 256 + threadIdx.x;
  if (i >= n4) return;
  float4 v = reinterpret_cast<const float4*>(in)[i];
  ushort4 o;
  o.x = f2bf(v.x); o.y = f2bf(v.y); o.z = f2bf(v.z); o.w = f2bf(v.w);
  reinterpret_cast<ushort4*>(out)[i] = o;
}

// C[M,N] = A[M,K](bf16) * W[N,K](bf16)^T + bias.
// MODE 0: Cout fp32 [M,N].  MODE 1: scatter to Q/K (b,h,s,d) and Vt (b,h,d,s) bf16.
// 128x128 tile, BK=64, 4 waves (2x2), 16x16x32 bf16 MFMA, global_load_lds staging.
template <int MODE, int N, int K>
__global__ __launch_bounds__(256) void gemm_bt(const unsigned short* __restrict__ A,
                                               const unsigned short* __restrict__ W,
                                               const float* __restrict__ bias,
                                               float* __restrict__ Cout,
                                               unsigned short* __restrict__ Qp,
                                               unsigned short* __restrict__ Kp,
                                               unsigned short* __restrict__ Vt) {
  __shared__ unsigned short As[128 * 64];
  __shared__ unsigned short Bs[128 * 64];
  const int tid = threadIdx.x;
  const int m0 = blockIdx.x * 128;
  const int n0 = blockIdx.y * 128;
  const int w = tid >> 6, lane = tid & 63, g = lane >> 4, lr = lane & 15;
  const int wr = w >> 1, wc = w & 1;

  f32x4 acc[4][4];
#pragma unroll
  for (int i = 0; i < 4; ++i)
#pragma unroll
    for (int j = 0; j < 4; ++j)
#pragma unroll
      for (int r = 0; r < 4; ++r) acc[i][j][r] = 0.f;

  for (int kt = 0; kt < K; kt += 64) {
    // stage A,B tiles: 1024 chunks of 16B each per tile, 4 per thread
#pragma unroll
    for (int it = 0; it < 4; ++it) {
      const int c = it * 256 + tid;
      const int row = c >> 3;
      const int colb = (c & 7) * 16;
      gload_lds16((const char*)(A + (size_t)(m0 + row) * K + kt) + colb, (char*)As + c * 16);
      gload_lds16((const char*)(W + (size_t)(n0 + row) * K + kt) + colb, (char*)Bs + c * 16);
    }
    __syncthreads();
#pragma unroll
    for (int ks = 0; ks < 2; ++ks) {
      bf16x8 af[4], bf[4];
#pragma unroll
      for (int mi = 0; mi < 4; ++mi)
        af[mi] = *(const bf16x8*)(As + (wr * 64 + mi * 16 + lr) * 64 + ks * 32 + g * 8);
#pragma unroll
      for (int ni = 0; ni < 4; ++ni)
        bf[ni] = *(const bf16x8*)(Bs + (wc * 64 + ni * 16 + lr) * 64 + ks * 32 + g * 8);
#pragma unroll
      for (int mi = 0; mi < 4; ++mi)
#pragma unroll
        for (int ni = 0; ni < 4; ++ni)
          acc[mi][ni] = __builtin_amdgcn_mfma_f32_16x16x32_bf16(af[mi], bf[ni], acc[mi][ni], 0, 0, 0);
    }
    __syncthreads();
  }

  if (MODE == 0) {
#pragma unroll
    for (int ni = 0; ni < 4; ++ni) {
      const int col = n0 + wc * 64 + ni * 16 + lr;
      const float bv = bias[col];
#pragma unroll
      for (int mi = 0; mi < 4; ++mi)
#pragma unroll
        for (int r = 0; r < 4; ++r) {
          const int row = m0 + wr * 64 + mi * 16 + g * 4 + r;
          Cout[(size_t)row * N + col] = acc[mi][ni][r] + bv;
        }
    }
  } else {
#pragma unroll
    for (int ni = 0; ni < 4; ++ni) {
      const int col = n0 + wc * 64 + ni * 16 + lr;
      const float bv = bias[col];
      const int which = col >> 10;
      const int h = (col >> 6) & 15;
      const int d = col & 63;
#pragma unroll
      for (int mi = 0; mi < 4; ++mi)
#pragma unroll
        for (int r = 0; r < 4; ++r) {
          const int row = m0 + wr * 64 + mi * 16 + g * 4 + r;
          const int b = row >> 11, s = row & 2047;
          const int bh = b * 16 + h;
          const unsigned short v = f2bf(acc[mi][ni][r] + bv);
          if (which == 0)      Qp[((size_t)bh * 2048 + s) * 64 + d] = v;
          else if (which == 1) Kp[((size_t)bh * 2048 + s) * 64 + d] = v;
          else                 Vt[((size_t)bh * 64 + d) * 2048 + s] = v;
        }
    }
  }
}

// Flash attention, causal. grid (B*H=32, S/16=128). ONE wave per block, 16 q-rows.
// KV block = 64. Online softmax per q-row (replicated across the 16-lane group via
// shfl_xor). P staged via per-wave LDS (XOR-swizzled); wave-internal DS ordering only
// (no __syncthreads) -> no block barriers, no vmcnt drain, deep TLP across 4096 blocks.
__global__ __launch_bounds__(64) void attn_fwd(const unsigned short* __restrict__ Q,
                                               const unsigned short* __restrict__ Kg,
                                               const unsigned short* __restrict__ Vt,
                                               unsigned short* __restrict__ AO) {
  const int bh = blockIdx.x;   // b*16 + h
  const int qt = blockIdx.y;   // 16-row q tile
  const int lane = threadIdx.x & 63;
  const int g = lane >> 4, lr = lane & 15;
  const int qrow0 = qt * 16;
  const unsigned short* Qp = Q  + (size_t)bh * 2048 * 64;
  const unsigned short* Kp = Kg + (size_t)bh * 2048 * 64;
  const unsigned short* Vp = Vt + (size_t)bh * 64 * 2048;

  __shared__ unsigned short Pl[16 * 64];  // 2 KB, single-wave private

  bf16x8 aq[2];
#pragma unroll
  for (int ks = 0; ks < 2; ++ks)
    aq[ks] = *(const bf16x8*)(Qp + (size_t)(qrow0 + lr) * 64 + ks * 32 + g * 8);

  f32x4 o[4];
  float m_r[4], l_r[4];
#pragma unroll
  for (int db = 0; db < 4; ++db)
#pragma unroll
    for (int r = 0; r < 4; ++r) o[db][r] = 0.f;
#pragma unroll
  for (int r = 0; r < 4; ++r) { m_r[r] = -INFINITY; l_r[r] = 0.f; }

  const int kv_end = qrow0 + 16;  // exclusive upper bound on needed keys
  for (int kvb = 0; kvb < kv_end; kvb += 64) {
    // ---- QK^T (scores) ----
    f32x4 sc[4];
#pragma unroll
    for (int f = 0; f < 4; ++f)
#pragma unroll
      for (int r = 0; r < 4; ++r) sc[f][r] = 0.f;
#pragma unroll
    for (int ks = 0; ks < 2; ++ks)
#pragma unroll
      for (int f = 0; f < 4; ++f) {
        bf16x8 bk = *(const bf16x8*)(Kp + (size_t)(kvb + f * 16 + lr) * 64 + ks * 32 + g * 8);
        sc[f] = __builtin_amdgcn_mfma_f32_16x16x32_bf16(aq[ks], bk, sc[f], 0, 0, 0);
      }

    // ---- prefetch V for this kv block (independent of scores; hides L2 latency
    //      under softmax; issued before the asm memory clobber below) ----
    bf16x8 bv[2][4];
#pragma unroll
    for (int ks = 0; ks < 2; ++ks)
#pragma unroll
      for (int db = 0; db < 4; ++db)
        bv[ks][db] = *(const bf16x8*)(Vp + (size_t)(db * 16 + lr) * 2048 + kvb + ks * 32 + g * 8);

    // ---- online softmax (per q-row, replicated over 16-lane group) ----
#pragma unroll
    for (int r = 0; r < 4; ++r) {
      const int qrow = qrow0 + g * 4 + r;
      float mx = -INFINITY;
#pragma unroll
      for (int f = 0; f < 4; ++f) {
        float s = sc[f][r] * 0.125f;                 // 1/sqrt(64)
        if (kvb + f * 16 + lr > qrow) s = -INFINITY; // causal mask
        sc[f][r] = s;
        mx = fmaxf(mx, s);
      }
      mx = fmaxf(mx, __shfl_xor(mx, 1));
      mx = fmaxf(mx, __shfl_xor(mx, 2));
      mx = fmaxf(mx, __shfl_xor(mx, 4));
      mx = fmaxf(mx, __shfl_xor(mx, 8));
      const float mn = fmaxf(m_r[r], mx);
      const float sc_old = __expf(m_r[r] - mn);
      float ps = 0.f;
#pragma unroll
      for (int f = 0; f < 4; ++f) {
        float p = __expf(sc[f][r] - mn);
        sc[f][r] = p;
        ps += p;
      }
      ps += __shfl_xor(ps, 1); ps += __shfl_xor(ps, 2);
      ps += __shfl_xor(ps, 4); ps += __shfl_xor(ps, 8);
      l_r[r] = l_r[r] * sc_old + ps;
      m_r[r] = mn;
#pragma unroll
      for (int db = 0; db < 4; ++db) o[db][r] *= sc_old;
    }

    // ---- P -> LDS (XOR swizzle), wave-internal ordering only ----
#pragma unroll
    for (int r = 0; r < 4; ++r) {
      const int prow = g * 4 + r;
#pragma unroll
      for (int f = 0; f < 4; ++f) {
        const int byte = (prow * 128 + (f * 16 + lr) * 2) ^ ((prow & 7) << 4);
        *(unsigned short*)((char*)Pl + byte) = f2bf(sc[f][r]);
      }
    }
    // DS ops of one wave complete in order; wait for writes, fence the scheduler
    // so the dependent ds_read/MFMA can't be hoisted above (rule #18).
    asm volatile("s_waitcnt lgkmcnt(0)" ::: "memory");
    __builtin_amdgcn_sched_barrier(0);

    // ---- PV ----
#pragma unroll
    for (int ks = 0; ks < 2; ++ks) {
      const int byte = (lr * 128 + ks * 64 + g * 16) ^ ((lr & 7) << 4);
      bf16x8 pa = *(const bf16x8*)((const char*)Pl + byte);
#pragma unroll
      for (int db = 0; db < 4; ++db)
        o[db] = __builtin_amdgcn_mfma_f32_16x16x32_bf16(pa, bv[ks][db], o[db], 0, 0, 0);
    }
  }

  const int b = bh >> 4, h = bh & 15;
#pragma unroll
  for (int r = 0; r < 4; ++r) {
    const float inv = 1.0f / l_r[r];
    const int row = qrow0 + g * 4 + r;
#pragma unroll
    for (int db = 0; db < 4; ++db)
      AO[(size_t)(b * 2048 + row) * 1024 + h * 64 + db * 16 + lr] = f2bf(o[db][r] * inv);
  }
}

extern "C" void kernel_launch(void* const* d_in, const int* in_sizes, int n_in,
                              void* d_out, int out_size, void* d_ws, size_t ws_size,
                              hipStream_t stream) {
  const float* x     = (const float*)d_in[0];
  const float* W_qkv = (const float*)d_in[1];
  const float* b_qkv = (const float*)d_in[2];
  const float* W_out = (const float*)d_in[3];
  const float* b_out = (const float*)d_in[4];
  float* out = (float*)d_out;

  // workspace layout (48 MB total, fully rewritten every call)
  char* ws = (char*)d_ws;
  unsigned short* xb  = (unsigned short*)(ws);                    // 8 MB x bf16 [4096,1024]
  unsigned short* wqb = (unsigned short*)(ws + ((size_t)8 << 20)); // 6 MB W_qkv bf16
  unsigned short* wob = (unsigned short*)(ws + ((size_t)14 << 20)); // 2 MB W_out bf16
  unsigned short* Qb  = (unsigned short*)(ws + ((size_t)16 << 20)); // 8 MB Q [b,h,s,d]
  unsigned short* Kb  = (unsigned short*)(ws + ((size_t)24 << 20)); // 8 MB K [b,h,s,d]
  unsigned short* Vtb = (unsigned short*)(ws + ((size_t)32 << 20)); // 8 MB V^T [b,h,d,s]
  unsigned short* AOb = (unsigned short*)(ws + ((size_t)40 << 20)); // 8 MB attn out [4096,1024]

  cvt_f32_bf16_k<<<4096, 256, 0, stream>>>(x, xb, 4096 * 1024 / 4);
  cvt_f32_bf16_k<<<3072, 256, 0, stream>>>(W_qkv, wqb, 3072 * 1024 / 4);
  cvt_f32_bf16_k<<<1024, 256, 0, stream>>>(W_out, wob, 1024 * 1024 / 4);

  gemm_bt<1, 3072, 1024><<<dim3(32, 24), 256, 0, stream>>>(xb, wqb, b_qkv, nullptr, Qb, Kb, Vtb);
  attn_fwd<<<dim3(32, 128), 64, 0, stream>>>(Qb, Kb, Vtb, AOb);
  gemm_bt<0, 1024, 1024><<<dim3(32, 8), 256, 0, stream>>>(AOb, wob, b_out, out, nullptr, nullptr, nullptr);
}